// Round 10
// baseline (153.700 us; speedup 1.0000x reference)
//
#include <hip/hip_runtime.h>
#include <hip/hip_cooperative_groups.h>

namespace cg = cooperative_groups;

#define SENT (-3.402823466e38f)

typedef __attribute__((ext_vector_type(8))) short short8;
typedef __attribute__((ext_vector_type(4))) float floatx4;

// ws float offsets
#define OFF_QKP   0         // ushort[512][512]  (qkp bf16, scale baked in)
#define OFF_AGG   131072    // ushort[512][512]  (agg bf16)
#define OFF_VNODE 262144    // float [512][256]

__device__ __forceinline__ ushort f2b(float f) {          // RNE fp32->bf16
    uint u = __float_as_uint(f);
    u += 0x7FFFu + ((u >> 16) & 1u);
    return (ushort)(u >> 16);
}
__device__ __forceinline__ short8 pk8(float4 a, float4 b) {
    short8 r;
    r[0]=(short)f2b(a.x); r[1]=(short)f2b(a.y); r[2]=(short)f2b(a.z); r[3]=(short)f2b(a.w);
    r[4]=(short)f2b(b.x); r[5]=(short)f2b(b.y); r[6]=(short)f2b(b.z); r[7]=(short)f2b(b.w);
    return r;
}

// ================= Cooperative single-dispatch kernel ======================
struct SMemA { float xL[16][264]; float red[4][64][4]; float qls[16][34]; };
struct SMemB { ushort edsA[128][72]; ushort qkpL[16][64]; float attL[8][132];
               ushort attT[16][136]; float mval[128]; };
struct SMemC { ushort yL[16][264]; float red2[4][64][4]; };
union  SMemU { SMemA a; SMemB b; SMemC c; };

__global__ __launch_bounds__(256, 2)
void kCoop(const float* __restrict__ x, const int* __restrict__ msk,
           const float* __restrict__ edge,
           const float* __restrict__ Wq, const float* __restrict__ bq,
           const float* __restrict__ Wk, const float* __restrict__ Wv,
           const float* __restrict__ bv, const float* __restrict__ Wp,
           const float* __restrict__ bp,
           ushort* qkp, ushort* agg, float* vnode, float* out) {
    __shared__ SMemU sm;
    cg::grid_group grid = cg::this_grid();
    int tid = threadIdx.x;
    int w = tid >> 6, lane = tid & 63, g = lane >> 4, r = lane & 15;
    int b = blockIdx.x;

    // Prefetch phase-B edge row into regs: in flight across all of phase A.
    float4 ef[8];
    {
        const float* eg = edge + (size_t)b * 8192;
        #pragma unroll
        for (int it = 0; it < 8; ++it)
            ef[it] = *(const float4*)(eg + (size_t)(tid + 256*it)*4);
    }

    // ---------------- Phase A: q -> qkp, vnode (MFMA, raw weights) ---------
    {
        int rt = b >> 4, ct = (b >> 1) & 7, m = b & 1;
        int r0 = rt*16, c0 = ct*32, h = ct;
        #pragma unroll
        for (int it = 0; it < 4; ++it) {    // stage x[16][256]
            int fid = (tid + 256*it)*4;
            int rr = fid >> 8, k = fid & 255;
            *(float4*)&sm.a.xL[rr][k] = *(const float4*)&x[(size_t)(r0+rr)*256 + k];
        }
        __syncthreads();
        int nt = w & 1, ks = w >> 1;        // n-subtile, K-half
        int c = c0 + nt*16 + r;
        const float* Wrow = m ? (Wv + (size_t)c*320) : (Wq + (size_t)c*256);
        floatx4 acc = {0.f,0.f,0.f,0.f};
        #pragma unroll
        for (int kt = ks*4; kt < ks*4+4; ++kt) {
            int k0 = kt*32 + g*8;
            short8 af = pk8(*(float4*)&sm.a.xL[r][k0], *(float4*)&sm.a.xL[r][k0+4]);
            short8 bf = pk8(*(const float4*)&Wrow[k0], *(const float4*)&Wrow[k0+4]);
            acc = __builtin_amdgcn_mfma_f32_16x16x32_bf16(af, bf, acc, 0,0,0);
        }
        *(floatx4*)&sm.a.red[w][lane][0] = acc;
        __syncthreads();
        {   // combine K-halves + bias
            int nt2 = tid >> 7, half = (tid >> 6) & 1, l = tid & 63;
            int g2 = l >> 4, r2 = l & 15;
            int c2 = c0 + nt2*16 + r2;
            #pragma unroll
            for (int ii = 0; ii < 2; ++ii) {
                int i = half*2 + ii;
                float v = sm.a.red[nt2][l][i] + sm.a.red[2+nt2][l][i];
                int row = 4*g2 + i;
                if (m == 0) sm.a.qls[row][nt2*16 + r2] = v + bq[c2];
                else vnode[(size_t)(r0 + row)*256 + c2] = v + bv[c2];
            }
        }
        __syncthreads();
        if (m == 0) {   // qkp: thread (rr, e-quad); raw Wk edge cols coalesced
            int rr = tid >> 4, e4 = (tid & 15)*4;
            const float* wk = Wk + (size_t)(h*32)*320 + 256 + e4;
            float a0=0.f, a1=0.f, a2=0.f, a3=0.f;
            #pragma unroll 8
            for (int d = 0; d < 32; ++d) {
                float qd = sm.a.qls[rr][d];
                float4 w4 = *(const float4*)&wk[(size_t)d*320];
                a0 += qd*w4.x; a1 += qd*w4.y; a2 += qd*w4.z; a3 += qd*w4.w;
            }
            const float s = 0.17677669529663687f;  // 1/sqrt(32)
            ushort4 u; u.x=f2b(a0*s); u.y=f2b(a1*s); u.z=f2b(a2*s); u.w=f2b(a3*s);
            *(ushort4*)&qkp[(size_t)(r0+rr)*512 + h*64 + e4] = u;
        }
    }
    grid.sync();

    // ---------------- Phase B: per-row attention (r9 k2) -------------------
    {
        int row = b;
        {   // qkp stage (+ zero pad rows 8..15)
            ushort* qf = (ushort*)sm.b.qkpL;
            *(uint*)&qf[tid*2]       = *(const uint*)&qkp[(size_t)row*512 + tid*2];
            *(uint*)&qf[512 + tid*2] = 0u;
        }
        if (tid < 128) sm.b.mval[tid] = (msk[(size_t)row*128 + tid] != 0) ? 1.0f : 0.0f;
        if (tid < 136) {
            #pragma unroll
            for (int hp = 8; hp < 16; ++hp) sm.b.attT[hp][tid] = 0;
        }
        #pragma unroll
        for (int it = 0; it < 8; ++it) {   // edge (prefetched) -> bf16 LDS
            int fid = (tid + 256*it)*4;
            int j = fid >> 6, e = fid & 63;
            uint lo = (uint)f2b(ef[it].x) | ((uint)f2b(ef[it].y) << 16);
            uint hi = (uint)f2b(ef[it].z) | ((uint)f2b(ef[it].w) << 16);
            *(uint2*)&sm.b.edsA[j][e] = make_uint2(lo, hi);
        }
        __syncthreads();

        {   // logits MFMA: D[j-local][h]; wave w -> mt = 2w, 2w+1
            #pragma unroll
            for (int mi = 0; mi < 2; ++mi) {
                int mt = w*2 + mi;
                floatx4 acc = {0,0,0,0};
                #pragma unroll
                for (int kt = 0; kt < 2; ++kt) {
                    short8 af = *(short8*)&sm.b.edsA[mt*16 + r][kt*32 + g*8];
                    short8 bf = *(short8*)&sm.b.qkpL[r][kt*32 + g*8];
                    acc = __builtin_amdgcn_mfma_f32_16x16x32_bf16(af, bf, acc, 0,0,0);
                }
                if (r < 8) {
                    #pragma unroll
                    for (int i = 0; i < 4; ++i) {
                        int j = mt*16 + 4*g + i;
                        sm.b.attL[r][j] = (sm.b.mval[j] > 0.5f) ? acc[i] : SENT;
                    }
                }
            }
        }
        __syncthreads();

        {   // softmax: wave w -> heads 2w, 2w+1
            #pragma unroll
            for (int hh = 0; hh < 2; ++hh) {
                int h = w*2 + hh;
                float v0 = sm.b.attL[h][lane];
                float v1 = sm.b.attL[h][64 + lane];
                float mx = fmaxf(v0, v1);
                #pragma unroll
                for (int off = 32; off >= 1; off >>= 1) mx = fmaxf(mx, __shfl_xor(mx, off));
                float e0 = __expf(v0 - mx), e1 = __expf(v1 - mx);
                float smm = e0 + e1;
                #pragma unroll
                for (int off = 32; off >= 1; off >>= 1) smm += __shfl_xor(smm, off);
                float inv = 1.0f / smm;
                sm.b.attT[h][lane]      = f2b(e0 * inv);
                sm.b.attT[h][64 + lane] = f2b(e1 * inv);
            }
        }
        __syncthreads();

        {   // agg MFMA: D[h][e]; wave w = e-tile
            floatx4 acc = {0,0,0,0};
            #pragma unroll
            for (int kt = 0; kt < 4; ++kt) {
                short8 a2 = *(short8*)&sm.b.attT[r][kt*32 + g*8];
                short8 b2;
                #pragma unroll
                for (int jj = 0; jj < 8; ++jj)
                    b2[jj] = (short)sm.b.edsA[kt*32 + g*8 + jj][w*16 + r];
                acc = __builtin_amdgcn_mfma_f32_16x16x32_bf16(a2, b2, acc, 0,0,0);
            }
            #pragma unroll
            for (int i = 0; i < 4; ++i) {
                int h = 4*g + i;
                if (h < 8)
                    agg[(size_t)row*512 + h*64 + w*16 + r] = f2b(acc[i]);
            }
        }
    }
    grid.sync();

    // ---------------- Phase C: y = vnode + agg@WvE^T; out = y@Wp^T + bp ----
    {
        int rt = b >> 4, ob = b & 15;
        int r0 = rt*16, o0 = ob*16;
        #pragma unroll
        for (int pi = 0; pi < 4; ++pi) {   // y: 16 (h,ntl) pairs over 4 waves
            int p = w*4 + pi, h = p >> 1, ntl = p & 1;
            int c = h*32 + ntl*16 + r;
            floatx4 acc;
            #pragma unroll
            for (int i = 0; i < 4; ++i)
                acc[i] = vnode[(size_t)(r0 + 4*g + i)*256 + c];
            #pragma unroll
            for (int kt = 0; kt < 2; ++kt) {
                short8 af = *(const short8*)&agg[(size_t)(r0 + r)*512 + h*64 + kt*32 + g*8];
                const float* wr = Wv + (size_t)c*320 + 256 + kt*32 + g*8;
                short8 bf = pk8(*(const float4*)wr, *(const float4*)(wr + 4));
                acc = __builtin_amdgcn_mfma_f32_16x16x32_bf16(af, bf, acc, 0,0,0);
            }
            #pragma unroll
            for (int i = 0; i < 4; ++i)
                sm.c.yL[4*g + i][c] = f2b(acc[i]);
        }
        __syncthreads();
        {   // out: one 16-o tile, K split over 4 waves
            int o = o0 + r;
            const float* wr = Wp + (size_t)o*256;
            floatx4 acc = {0,0,0,0};
            #pragma unroll
            for (int kt = w*2; kt < w*2+2; ++kt) {
                int k0 = kt*32 + g*8;
                short8 af = *(short8*)&sm.c.yL[r][k0];
                short8 bf = pk8(*(const float4*)&wr[k0], *(const float4*)&wr[k0+4]);
                acc = __builtin_amdgcn_mfma_f32_16x16x32_bf16(af, bf, acc, 0,0,0);
            }
            *(floatx4*)&sm.c.red2[w][lane][0] = acc;
        }
        __syncthreads();
        {
            int l = tid >> 2, i = tid & 3;
            float v = sm.c.red2[0][l][i] + sm.c.red2[1][l][i]
                    + sm.c.red2[2][l][i] + sm.c.red2[3][l][i];
            int o = o0 + (l & 15);
            int row = r0 + 4*(l >> 4) + i;
            out[(size_t)row*256 + o] = v + bp[o];
        }
    }
}

// ================= Fallback: proven r9 three-kernel path ===================
__global__ __launch_bounds__(256, 4)
void k1_proj(const float* __restrict__ x, const float* __restrict__ Wq,
             const float* __restrict__ Wv, const float* __restrict__ Wk,
             const float* __restrict__ bq, const float* __restrict__ bv,
             float* __restrict__ vnode, ushort* __restrict__ qkp) {
    __shared__ float xL[16][264];
    __shared__ float qls[16][66];
    int tid = threadIdx.x;
    int w = tid >> 6, lane = tid & 63, g = lane >> 4, r = lane & 15;
    int m  = blockIdx.x & 1;
    int ct = (blockIdx.x >> 1) & 3;
    int rt = blockIdx.x >> 3;
    int r0 = rt*16, c0 = ct*64;

    #pragma unroll
    for (int it = 0; it < 4; ++it) {
        int fid = (tid + 256*it)*4;
        int rr = fid >> 8, k = fid & 255;
        *(float4*)&xL[rr][k] = *(const float4*)&x[(size_t)(r0+rr)*256 + k];
    }
    __syncthreads();

    int c = c0 + w*16 + r;
    const float* Wrow = m ? (Wv + (size_t)c*320) : (Wq + (size_t)c*256);
    floatx4 acc = {0.f,0.f,0.f,0.f};
    #pragma unroll
    for (int kt = 0; kt < 8; ++kt) {
        int k0 = kt*32 + g*8;
        short8 af = pk8(*(float4*)&xL[r][k0], *(float4*)&xL[r][k0+4]);
        short8 bf = pk8(*(const float4*)&Wrow[k0], *(const float4*)&Wrow[k0+4]);
        acc = __builtin_amdgcn_mfma_f32_16x16x32_bf16(af, bf, acc, 0,0,0);
    }
    float bb = m ? bv[c] : bq[c];
    if (m) {
        #pragma unroll
        for (int i = 0; i < 4; ++i)
            vnode[(size_t)(r0 + 4*g + i)*256 + c] = acc[i] + bb;
    } else {
        #pragma unroll
        for (int i = 0; i < 4; ++i)
            qls[4*g + i][w*16 + r] = acc[i] + bb;
        __syncthreads();
        int rr = tid >> 4, es = tid & 15;
        int h0 = ct*2;
        float a0[4] = {0,0,0,0}, a1[4] = {0,0,0,0};
        const float* wk0 = Wk + (size_t)(h0*32)*320 + 256 + es*4;
        const float* wk1 = Wk + (size_t)((h0+1)*32)*320 + 256 + es*4;
        #pragma unroll 8
        for (int d = 0; d < 32; ++d) {
            float q0 = qls[rr][d];
            float q1 = qls[rr][32 + d];
            float4 w0 = *(const float4*)&wk0[(size_t)d*320];
            float4 w1 = *(const float4*)&wk1[(size_t)d*320];
            a0[0]+=q0*w0.x; a0[1]+=q0*w0.y; a0[2]+=q0*w0.z; a0[3]+=q0*w0.w;
            a1[0]+=q1*w1.x; a1[1]+=q1*w1.y; a1[2]+=q1*w1.z; a1[3]+=q1*w1.w;
        }
        const float s = 0.17677669529663687f;
        ushort4 u0, u1;
        u0.x=f2b(a0[0]*s); u0.y=f2b(a0[1]*s); u0.z=f2b(a0[2]*s); u0.w=f2b(a0[3]*s);
        u1.x=f2b(a1[0]*s); u1.y=f2b(a1[1]*s); u1.z=f2b(a1[2]*s); u1.w=f2b(a1[3]*s);
        size_t base = (size_t)(r0 + rr)*512;
        *(ushort4*)&qkp[base + h0*64 + es*4]     = u0;
        *(ushort4*)&qkp[base + (h0+1)*64 + es*4] = u1;
    }
}

__global__ __launch_bounds__(256, 4)
void k2_attn(const float* __restrict__ edge, const int* __restrict__ msk,
             const ushort* __restrict__ qkp, ushort* __restrict__ aggO) {
    __shared__ ushort edsA[128][72];
    __shared__ ushort qkpL[16][64];
    __shared__ float  attL[8][132];
    __shared__ ushort attT[16][136];
    __shared__ float  mval[128];
    int tid = threadIdx.x;
    int w = tid >> 6, lane = tid & 63, g = lane >> 4, r = lane & 15;
    int row = blockIdx.x;

    float4 ef[8];
    const float* eg = edge + (size_t)row*8192;
    #pragma unroll
    for (int it = 0; it < 8; ++it)
        ef[it] = *(const float4*)(eg + (size_t)(tid + 256*it)*4);

    {
        ushort* qf = (ushort*)qkpL;
        *(uint*)&qf[tid*2]       = *(const uint*)&qkp[(size_t)row*512 + tid*2];
        *(uint*)&qf[512 + tid*2] = 0u;
    }
    if (tid < 128) mval[tid] = (msk[(size_t)row*128 + tid] != 0) ? 1.0f : 0.0f;
    if (tid < 136) {
        #pragma unroll
        for (int hp = 8; hp < 16; ++hp) attT[hp][tid] = 0;
    }
    #pragma unroll
    for (int it = 0; it < 8; ++it) {
        int fid = (tid + 256*it)*4;
        int j = fid >> 6, e = fid & 63;
        uint lo = (uint)f2b(ef[it].x) | ((uint)f2b(ef[it].y) << 16);
        uint hi = (uint)f2b(ef[it].z) | ((uint)f2b(ef[it].w) << 16);
        *(uint2*)&edsA[j][e] = make_uint2(lo, hi);
    }
    __syncthreads();

    {
        #pragma unroll
        for (int mi = 0; mi < 2; ++mi) {
            int mt = w*2 + mi;
            floatx4 acc = {0,0,0,0};
            #pragma unroll
            for (int kt = 0; kt < 2; ++kt) {
                short8 af = *(short8*)&edsA[mt*16 + r][kt*32 + g*8];
                short8 bf = *(short8*)&qkpL[r][kt*32 + g*8];
                acc = __builtin_amdgcn_mfma_f32_16x16x32_bf16(af, bf, acc, 0,0,0);
            }
            if (r < 8) {
                #pragma unroll
                for (int i = 0; i < 4; ++i) {
                    int j = mt*16 + 4*g + i;
                    attL[r][j] = (mval[j] > 0.5f) ? acc[i] : SENT;
                }
            }
        }
    }
    __syncthreads();

    {
        #pragma unroll
        for (int hh = 0; hh < 2; ++hh) {
            int h = w*2 + hh;
            float v0 = attL[h][lane];
            float v1 = attL[h][64 + lane];
            float mx = fmaxf(v0, v1);
            #pragma unroll
            for (int off = 32; off >= 1; off >>= 1) mx = fmaxf(mx, __shfl_xor(mx, off));
            float e0 = __expf(v0 - mx), e1 = __expf(v1 - mx);
            float smv = e0 + e1;
            #pragma unroll
            for (int off = 32; off >= 1; off >>= 1) smv += __shfl_xor(smv, off);
            float inv = 1.0f / smv;
            attT[h][lane]      = f2b(e0 * inv);
            attT[h][64 + lane] = f2b(e1 * inv);
        }
    }
    __syncthreads();

    {
        floatx4 acc = {0,0,0,0};
        #pragma unroll
        for (int kt = 0; kt < 4; ++kt) {
            short8 a2 = *(short8*)&attT[r][kt*32 + g*8];
            short8 b2;
            #pragma unroll
            for (int jj = 0; jj < 8; ++jj)
                b2[jj] = (short)edsA[kt*32 + g*8 + jj][w*16 + r];
            acc = __builtin_amdgcn_mfma_f32_16x16x32_bf16(a2, b2, acc, 0,0,0);
        }
        #pragma unroll
        for (int i = 0; i < 4; ++i) {
            int h = 4*g + i;
            if (h < 8)
                aggO[(size_t)row*512 + h*64 + w*16 + r] = f2b(acc[i]);
        }
    }
}

__global__ __launch_bounds__(256, 2)
void k3_out(const float* __restrict__ vnode, const ushort* __restrict__ aggI,
            const float* __restrict__ Wv, const float* __restrict__ Wp,
            const float* __restrict__ bp, float* __restrict__ out) {
    __shared__ ushort yL[16][264];
    int tid = threadIdx.x;
    int w = tid >> 6, lane = tid & 63, g = lane >> 4, r = lane & 15;
    int rt = blockIdx.x >> 2, ob = blockIdx.x & 3;
    int r0 = rt*16, o0 = ob*64;

    {
        #pragma unroll
        for (int pi = 0; pi < 4; ++pi) {
            int p = w*4 + pi, h = p >> 1, ntl = p & 1;
            int c = h*32 + ntl*16 + r;
            floatx4 acc;
            #pragma unroll
            for (int i = 0; i < 4; ++i)
                acc[i] = vnode[(size_t)(r0 + 4*g + i)*256 + c];
            #pragma unroll
            for (int kt = 0; kt < 2; ++kt) {
                short8 af = *(const short8*)&aggI[(size_t)(r0 + r)*512 + h*64 + kt*32 + g*8];
                const float* wr = Wv + (size_t)c*320 + 256 + kt*32 + g*8;
                short8 bf = pk8(*(const float4*)wr, *(const float4*)(wr + 4));
                acc = __builtin_amdgcn_mfma_f32_16x16x32_bf16(af, bf, acc, 0,0,0);
            }
            #pragma unroll
            for (int i = 0; i < 4; ++i)
                yL[4*g + i][c] = f2b(acc[i]);
        }
    }
    __syncthreads();

    {
        int o = o0 + w*16 + r;
        floatx4 acc = {0,0,0,0};
        const float* wr = Wp + (size_t)o*256;
        #pragma unroll
        for (int kt = 0; kt < 8; ++kt) {
            int k0 = kt*32 + g*8;
            short8 af = *(short8*)&yL[r][k0];
            short8 bf = pk8(*(const float4*)&wr[k0], *(const float4*)&wr[k0+4]);
            acc = __builtin_amdgcn_mfma_f32_16x16x32_bf16(af, bf, acc, 0,0,0);
        }
        float bb = bp[o];
        #pragma unroll
        for (int i = 0; i < 4; ++i)
            out[(size_t)(r0 + 4*g + i)*256 + o] = acc[i] + bb;
    }
}

extern "C" void kernel_launch(void* const* d_in, const int* in_sizes, int n_in,
                              void* d_out, int out_size, void* d_ws, size_t ws_size,
                              hipStream_t stream) {
    (void)in_sizes; (void)n_in; (void)out_size; (void)ws_size;
    const float* x    = (const float*)d_in[0];
    // d_in[1] aux_x: unused by reference
    const int*   msk  = (const int*)d_in[2];
    const float* edge = (const float*)d_in[3];
    const float* Wq   = (const float*)d_in[4];
    const float* bq   = (const float*)d_in[5];
    const float* Wk   = (const float*)d_in[6];
    // d_in[7] bk: constant over j -> cancels in softmax
    const float* Wv   = (const float*)d_in[8];
    const float* bv   = (const float*)d_in[9];
    const float* Wp   = (const float*)d_in[10];
    const float* bp   = (const float*)d_in[11];
    float* out = (float*)d_out;
    float* ws  = (float*)d_ws;

    ushort* qkp   = (ushort*)(ws + OFF_QKP);
    ushort* agg   = (ushort*)(ws + OFF_AGG);
    float*  vnode = ws + OFF_VNODE;

    void* args[] = { (void*)&x, (void*)&msk, (void*)&edge, (void*)&Wq, (void*)&bq,
                     (void*)&Wk, (void*)&Wv, (void*)&bv, (void*)&Wp, (void*)&bp,
                     (void*)&qkp, (void*)&agg, (void*)&vnode, (void*)&out };
    hipError_t err = hipLaunchCooperativeKernel(kCoop, dim3(512), dim3(256),
                                                args, 0u, stream);
    if (err != hipSuccess) {
        // fallback: proven 3-kernel pipeline (r9, 21.5 us)
        k1_proj<<<256, 256, 0, stream>>>(x, Wq, Wv, Wk, bq, bv, vnode, qkp);
        k2_attn<<<512, 256, 0, stream>>>(edge, msk, qkp, agg);
        k3_out<<<128, 256, 0, stream>>>(vnode, agg, Wv, Wp, bp, out);
    }
}

// Round 11
// 24.117 us; speedup vs baseline: 6.3732x; 6.3732x over previous
//
#include <hip/hip_runtime.h>

#define SENT (-3.402823466e38f)

typedef __attribute__((ext_vector_type(8))) short short8;
typedef __attribute__((ext_vector_type(4))) float floatx4;

// ws float offsets
#define OFF_QKP   0         // ushort[512][512]  (qkp bf16, scale baked in)
#define OFF_AGG   131072    // ushort[512][512]  (agg bf16)
#define OFF_VNODE 262144    // float [512][256]

__device__ __forceinline__ ushort f2b(float f) {          // RNE fp32->bf16
    uint u = __float_as_uint(f);
    u += 0x7FFFu + ((u >> 16) & 1u);
    return (ushort)(u >> 16);
}
__device__ __forceinline__ short8 pk8(float4 a, float4 b) {
    short8 r;
    r[0]=(short)f2b(a.x); r[1]=(short)f2b(a.y); r[2]=(short)f2b(a.z); r[3]=(short)f2b(a.w);
    r[4]=(short)f2b(b.x); r[5]=(short)f2b(b.y); r[6]=(short)f2b(b.z); r[7]=(short)f2b(b.w);
    return r;
}

// ---------------- K1: q -> qkp, vnode (validated kCoop phase A) ------------
// grid 512 = rt(32) x ct(8) x m(2), 256 thr. K split over waves + LDS combine.
__global__ __launch_bounds__(256, 4)
void k1_proj(const float* __restrict__ x,
             const float* __restrict__ Wq, const float* __restrict__ bq,
             const float* __restrict__ Wk, const float* __restrict__ Wv,
             const float* __restrict__ bv,
             float* __restrict__ vnode, ushort* __restrict__ qkp) {
    __shared__ float xL[16][264];
    __shared__ float red[4][64][4];
    __shared__ float qls[16][34];
    int tid = threadIdx.x;
    int w = tid >> 6, lane = tid & 63, g = lane >> 4, r = lane & 15;
    int b = blockIdx.x;
    int rt = b >> 4, ct = (b >> 1) & 7, m = b & 1;
    int r0 = rt*16, c0 = ct*32, h = ct;

    #pragma unroll
    for (int it = 0; it < 4; ++it) {    // stage x[16][256]
        int fid = (tid + 256*it)*4;
        int rr = fid >> 8, k = fid & 255;
        *(float4*)&xL[rr][k] = *(const float4*)&x[(size_t)(r0+rr)*256 + k];
    }
    __syncthreads();

    int nt = w & 1, ks = w >> 1;        // n-subtile, K-half
    int c = c0 + nt*16 + r;
    const float* Wrow = m ? (Wv + (size_t)c*320) : (Wq + (size_t)c*256);
    floatx4 acc = {0.f,0.f,0.f,0.f};
    #pragma unroll
    for (int kt = ks*4; kt < ks*4+4; ++kt) {
        int k0 = kt*32 + g*8;
        short8 af = pk8(*(float4*)&xL[r][k0], *(float4*)&xL[r][k0+4]);
        short8 bf = pk8(*(const float4*)&Wrow[k0], *(const float4*)&Wrow[k0+4]);
        acc = __builtin_amdgcn_mfma_f32_16x16x32_bf16(af, bf, acc, 0,0,0);
    }
    *(floatx4*)&red[w][lane][0] = acc;
    __syncthreads();

    {   // combine K-halves + bias
        int nt2 = tid >> 7, half = (tid >> 6) & 1, l = tid & 63;
        int g2 = l >> 4, r2 = l & 15;
        int c2 = c0 + nt2*16 + r2;
        #pragma unroll
        for (int ii = 0; ii < 2; ++ii) {
            int i = half*2 + ii;
            float v = red[nt2][l][i] + red[2+nt2][l][i];
            int row = 4*g2 + i;
            if (m == 0) qls[row][nt2*16 + r2] = v + bq[c2];
            else vnode[(size_t)(r0 + row)*256 + c2] = v + bv[c2];
        }
    }
    __syncthreads();

    if (m == 0) {   // qkp: thread (rr, e-quad); raw Wk edge cols coalesced
        int rr = tid >> 4, e4 = (tid & 15)*4;
        const float* wk = Wk + (size_t)(h*32)*320 + 256 + e4;
        float a0=0.f, a1=0.f, a2=0.f, a3=0.f;
        #pragma unroll 8
        for (int d = 0; d < 32; ++d) {
            float qd = qls[rr][d];
            float4 w4 = *(const float4*)&wk[(size_t)d*320];
            a0 += qd*w4.x; a1 += qd*w4.y; a2 += qd*w4.z; a3 += qd*w4.w;
        }
        const float s = 0.17677669529663687f;  // 1/sqrt(32)
        ushort4 u; u.x=f2b(a0*s); u.y=f2b(a1*s); u.z=f2b(a2*s); u.w=f2b(a3*s);
        *(ushort4*)&qkp[(size_t)(r0+rr)*512 + h*64 + e4] = u;
    }
}

// ---------------- K2: per-row attention, 512 thr (16 waves/CU) -------------
// grid 512, block = one (b,i) row. Logits: wave = j-tile. Softmax: wave = head.
__global__ __launch_bounds__(512, 4)
void k2_attn(const float* __restrict__ edge, const int* __restrict__ msk,
             const ushort* __restrict__ qkp, ushort* __restrict__ aggO) {
    __shared__ ushort edsA[128][72];
    __shared__ ushort qkpL[16][64];
    __shared__ float  attL[8][132];
    __shared__ ushort attT[16][136];
    __shared__ float  mval[128];
    int tid = threadIdx.x;
    int w = tid >> 6, lane = tid & 63, g = lane >> 4, r = lane & 15;
    int row = blockIdx.x;

    float4 ef[4];
    const float* eg = edge + (size_t)row*8192;
    #pragma unroll
    for (int it = 0; it < 4; ++it)
        ef[it] = *(const float4*)(eg + (size_t)(tid + 512*it)*4);

    if (tid < 256) {   // qkp stage (+ zero pad rows 8..15)
        ushort* qf = (ushort*)qkpL;
        *(uint*)&qf[tid*2]        = *(const uint*)&qkp[(size_t)row*512 + tid*2];
        *(uint*)&qf[512 + tid*2]  = 0u;
    }
    if (tid < 128) mval[tid] = (msk[(size_t)row*128 + tid] != 0) ? 1.0f : 0.0f;
    if (tid < 136) {
        #pragma unroll
        for (int hp = 8; hp < 16; ++hp) attT[hp][tid] = 0;
    }
    #pragma unroll
    for (int it = 0; it < 4; ++it) {   // edge -> bf16 LDS
        int fid = (tid + 512*it)*4;
        int j = fid >> 6, e = fid & 63;
        uint lo = (uint)f2b(ef[it].x) | ((uint)f2b(ef[it].y) << 16);
        uint hi = (uint)f2b(ef[it].z) | ((uint)f2b(ef[it].w) << 16);
        *(uint2*)&edsA[j][e] = make_uint2(lo, hi);
    }
    __syncthreads();

    {   // logits MFMA: D[j-local][h]; wave w = j-tile mt
        int mt = w;
        floatx4 acc = {0,0,0,0};
        #pragma unroll
        for (int kt = 0; kt < 2; ++kt) {
            short8 af = *(short8*)&edsA[mt*16 + r][kt*32 + g*8];
            short8 bf = *(short8*)&qkpL[r][kt*32 + g*8];
            acc = __builtin_amdgcn_mfma_f32_16x16x32_bf16(af, bf, acc, 0,0,0);
        }
        if (r < 8) {
            #pragma unroll
            for (int i = 0; i < 4; ++i) {
                int j = mt*16 + 4*g + i;
                attL[r][j] = (mval[j] > 0.5f) ? acc[i] : SENT;
            }
        }
    }
    __syncthreads();

    {   // softmax: wave w = head w
        int h = w;
        float v0 = attL[h][lane];
        float v1 = attL[h][64 + lane];
        float mx = fmaxf(v0, v1);
        #pragma unroll
        for (int off = 32; off >= 1; off >>= 1) mx = fmaxf(mx, __shfl_xor(mx, off));
        float e0 = __expf(v0 - mx), e1 = __expf(v1 - mx);
        float smv = e0 + e1;
        #pragma unroll
        for (int off = 32; off >= 1; off >>= 1) smv += __shfl_xor(smv, off);
        float inv = 1.0f / smv;
        attT[h][lane]      = f2b(e0 * inv);
        attT[h][64 + lane] = f2b(e1 * inv);
    }
    __syncthreads();

    if (w < 4) {   // agg MFMA: D[h][e]; wave w = e-tile
        floatx4 acc = {0,0,0,0};
        #pragma unroll
        for (int kt = 0; kt < 4; ++kt) {
            short8 a2 = *(short8*)&attT[r][kt*32 + g*8];
            short8 b2;
            #pragma unroll
            for (int jj = 0; jj < 8; ++jj)
                b2[jj] = (short)edsA[kt*32 + g*8 + jj][w*16 + r];
            acc = __builtin_amdgcn_mfma_f32_16x16x32_bf16(a2, b2, acc, 0,0,0);
        }
        #pragma unroll
        for (int i = 0; i < 4; ++i) {
            int h = 4*g + i;
            if (h < 8)
                aggO[(size_t)row*512 + h*64 + w*16 + r] = f2b(acc[i]);
        }
    }
}

// ---------------- K3: y + out proj (validated kCoop phase C) ---------------
// grid 512 = rt(32) x ob(16), 256 thr. 16-row x 16-o tiles, K-split combine.
__global__ __launch_bounds__(256, 4)
void k3_out(const float* __restrict__ vnode, const ushort* __restrict__ agg,
            const float* __restrict__ Wv, const float* __restrict__ Wp,
            const float* __restrict__ bp, float* __restrict__ out) {
    __shared__ ushort yL[16][264];
    __shared__ float red2[4][64][4];
    int tid = threadIdx.x;
    int w = tid >> 6, lane = tid & 63, g = lane >> 4, r = lane & 15;
    int b = blockIdx.x;
    int rt = b >> 4, ob = b & 15;
    int r0 = rt*16, o0 = ob*16;

    #pragma unroll
    for (int pi = 0; pi < 4; ++pi) {   // y: 16 (h,ntl) pairs over 4 waves
        int p = w*4 + pi, h = p >> 1, ntl = p & 1;
        int c = h*32 + ntl*16 + r;
        floatx4 acc;
        #pragma unroll
        for (int i = 0; i < 4; ++i)
            acc[i] = vnode[(size_t)(r0 + 4*g + i)*256 + c];
        #pragma unroll
        for (int kt = 0; kt < 2; ++kt) {
            short8 af = *(const short8*)&agg[(size_t)(r0 + r)*512 + h*64 + kt*32 + g*8];
            const float* wr = Wv + (size_t)c*320 + 256 + kt*32 + g*8;
            short8 bf = pk8(*(const float4*)wr, *(const float4*)(wr + 4));
            acc = __builtin_amdgcn_mfma_f32_16x16x32_bf16(af, bf, acc, 0,0,0);
        }
        #pragma unroll
        for (int i = 0; i < 4; ++i)
            yL[4*g + i][c] = f2b(acc[i]);
    }
    __syncthreads();

    {   // out: one 16-o tile, K split over 4 waves
        int o = o0 + r;
        const float* wr = Wp + (size_t)o*256;
        floatx4 acc = {0,0,0,0};
        #pragma unroll
        for (int kt = w*2; kt < w*2+2; ++kt) {
            int k0 = kt*32 + g*8;
            short8 af = *(short8*)&yL[r][k0];
            short8 bf = pk8(*(const float4*)&wr[k0], *(const float4*)&wr[k0+4]);
            acc = __builtin_amdgcn_mfma_f32_16x16x32_bf16(af, bf, acc, 0,0,0);
        }
        *(floatx4*)&red2[w][lane][0] = acc;
    }
    __syncthreads();

    {
        int l = tid >> 2, i = tid & 3;
        float v = red2[0][l][i] + red2[1][l][i] + red2[2][l][i] + red2[3][l][i];
        int o = o0 + (l & 15);
        int row = r0 + 4*(l >> 4) + i;
        out[(size_t)row*256 + o] = v + bp[o];
    }
}

extern "C" void kernel_launch(void* const* d_in, const int* in_sizes, int n_in,
                              void* d_out, int out_size, void* d_ws, size_t ws_size,
                              hipStream_t stream) {
    (void)in_sizes; (void)n_in; (void)out_size; (void)ws_size;
    const float* x    = (const float*)d_in[0];
    // d_in[1] aux_x: unused by reference
    const int*   msk  = (const int*)d_in[2];
    const float* edge = (const float*)d_in[3];
    const float* Wq   = (const float*)d_in[4];
    const float* bq   = (const float*)d_in[5];
    const float* Wk   = (const float*)d_in[6];
    // d_in[7] bk: constant over j -> cancels in softmax
    const float* Wv   = (const float*)d_in[8];
    const float* bv   = (const float*)d_in[9];
    const float* Wp   = (const float*)d_in[10];
    const float* bp   = (const float*)d_in[11];
    float* out = (float*)d_out;
    float* ws  = (float*)d_ws;

    ushort* qkp   = (ushort*)(ws + OFF_QKP);
    ushort* agg   = (ushort*)(ws + OFF_AGG);
    float*  vnode = ws + OFF_VNODE;

    k1_proj<<<512, 256, 0, stream>>>(x, Wq, bq, Wk, Wv, bv, vnode, qkp);
    k2_attn<<<512, 512, 0, stream>>>(edge, msk, qkp, agg);
    k3_out<<<512, 256, 0, stream>>>(vnode, agg, Wv, Wp, bp, out);
}

// Round 12
// 21.412 us; speedup vs baseline: 7.1782x; 1.1263x over previous
//
#include <hip/hip_runtime.h>

#define SENT (-3.402823466e38f)

typedef __attribute__((ext_vector_type(8))) short short8;
typedef __attribute__((ext_vector_type(4))) float floatx4;

// ws float offsets
#define OFF_QKP   0         // ushort[512][512]  (qkp bf16, scale baked in)
#define OFF_AGG   131072    // ushort[512][512]  (agg bf16)
#define OFF_VNODE 262144    // float [512][256]

__device__ __forceinline__ ushort f2b(float f) {          // RNE fp32->bf16
    uint u = __float_as_uint(f);
    u += 0x7FFFu + ((u >> 16) & 1u);
    return (ushort)(u >> 16);
}
__device__ __forceinline__ short8 pk8(float4 a, float4 b) {
    short8 r;
    r[0]=(short)f2b(a.x); r[1]=(short)f2b(a.y); r[2]=(short)f2b(a.z); r[3]=(short)f2b(a.w);
    r[4]=(short)f2b(b.x); r[5]=(short)f2b(b.y); r[6]=(short)f2b(b.z); r[7]=(short)f2b(b.w);
    return r;
}

// ---------------- K1: q -> qkp, vnode. MFMA with RAW weights (r9 exact) ----
// grid 256 = (rt 32 x ct 4 x m 2), 256 thr (4 waves). Block: 16 rows x 64 c.
__global__ __launch_bounds__(256, 4)
void k1_proj(const float* __restrict__ x, const float* __restrict__ Wq,
             const float* __restrict__ Wv, const float* __restrict__ Wk,
             const float* __restrict__ bq, const float* __restrict__ bv,
             float* __restrict__ vnode, ushort* __restrict__ qkp) {
    __shared__ float xL[16][264];   // stride 264 (16B-aligned rows)
    __shared__ float qls[16][66];   // q slice [row][c-local 64]
    int tid = threadIdx.x;
    int w = tid >> 6, lane = tid & 63, g = lane >> 4, r = lane & 15;
    int m  = blockIdx.x & 1;
    int ct = (blockIdx.x >> 1) & 3;
    int rt = blockIdx.x >> 3;
    int r0 = rt*16, c0 = ct*64;

    #pragma unroll
    for (int it = 0; it < 4; ++it) {     // stage x[16][256]
        int fid = (tid + 256*it)*4;
        int rr = fid >> 8, k = fid & 255;
        *(float4*)&xL[rr][k] = *(const float4*)&x[(size_t)(r0+rr)*256 + k];
    }
    __syncthreads();

    int c = c0 + w*16 + r;               // B-frag col (lane&15 = n)
    const float* Wrow = m ? (Wv + (size_t)c*320) : (Wq + (size_t)c*256);
    floatx4 acc = {0.f,0.f,0.f,0.f};
    #pragma unroll
    for (int kt = 0; kt < 8; ++kt) {
        int k0 = kt*32 + g*8;
        short8 af = pk8(*(float4*)&xL[r][k0], *(float4*)&xL[r][k0+4]);
        short8 bf = pk8(*(const float4*)&Wrow[k0], *(const float4*)&Wrow[k0+4]);
        acc = __builtin_amdgcn_mfma_f32_16x16x32_bf16(af, bf, acc, 0,0,0);
    }
    float bb = m ? bv[c] : bq[c];
    if (m) {   // vnode out (D: row=4g+i, col=r)
        #pragma unroll
        for (int i = 0; i < 4; ++i)
            vnode[(size_t)(r0 + 4*g + i)*256 + c] = acc[i] + bb;
    } else {   // q slice -> LDS, then qkp (raw Wk edge cols, coalesced)
        #pragma unroll
        for (int i = 0; i < 4; ++i)
            qls[4*g + i][w*16 + r] = acc[i] + bb;
        __syncthreads();
        int rr = tid >> 4, es = tid & 15;        // row, e-quad
        int h0 = ct*2;
        float a0[4] = {0,0,0,0}, a1[4] = {0,0,0,0};
        const float* wk0 = Wk + (size_t)(h0*32)*320 + 256 + es*4;
        const float* wk1 = Wk + (size_t)((h0+1)*32)*320 + 256 + es*4;
        #pragma unroll 8
        for (int d = 0; d < 32; ++d) {
            float q0 = qls[rr][d];
            float q1 = qls[rr][32 + d];
            float4 w0 = *(const float4*)&wk0[(size_t)d*320];
            float4 w1 = *(const float4*)&wk1[(size_t)d*320];
            a0[0]+=q0*w0.x; a0[1]+=q0*w0.y; a0[2]+=q0*w0.z; a0[3]+=q0*w0.w;
            a1[0]+=q1*w1.x; a1[1]+=q1*w1.y; a1[2]+=q1*w1.z; a1[3]+=q1*w1.w;
        }
        const float s = 0.17677669529663687f;    // 1/sqrt(32)
        ushort4 u0, u1;
        u0.x=f2b(a0[0]*s); u0.y=f2b(a0[1]*s); u0.z=f2b(a0[2]*s); u0.w=f2b(a0[3]*s);
        u1.x=f2b(a1[0]*s); u1.y=f2b(a1[1]*s); u1.z=f2b(a1[2]*s); u1.w=f2b(a1[3]*s);
        size_t base = (size_t)(r0 + rr)*512;
        *(ushort4*)&qkp[base + h0*64 + es*4]     = u0;
        *(ushort4*)&qkp[base + (h0+1)*64 + es*4] = u1;
    }
}

// ---------------- K2: per-row attention, 512 thr (isolated variable) -------
// grid 512, block = one (b,i) row. Logits: wave = j-tile. Softmax: wave = head.
__global__ __launch_bounds__(512, 4)
void k2_attn(const float* __restrict__ edge, const int* __restrict__ msk,
             const ushort* __restrict__ qkp, ushort* __restrict__ aggO) {
    __shared__ ushort edsA[128][72];
    __shared__ ushort qkpL[16][64];
    __shared__ float  attL[8][132];
    __shared__ ushort attT[16][136];
    __shared__ float  mval[128];
    int tid = threadIdx.x;
    int w = tid >> 6, lane = tid & 63, g = lane >> 4, r = lane & 15;
    int row = blockIdx.x;

    float4 ef[4];
    const float* eg = edge + (size_t)row*8192;
    #pragma unroll
    for (int it = 0; it < 4; ++it)
        ef[it] = *(const float4*)(eg + (size_t)(tid + 512*it)*4);

    if (tid < 256) {   // qkp stage (+ zero pad rows 8..15)
        ushort* qf = (ushort*)qkpL;
        *(uint*)&qf[tid*2]        = *(const uint*)&qkp[(size_t)row*512 + tid*2];
        *(uint*)&qf[512 + tid*2]  = 0u;
    }
    if (tid < 128) mval[tid] = (msk[(size_t)row*128 + tid] != 0) ? 1.0f : 0.0f;
    if (tid < 136) {
        #pragma unroll
        for (int hp = 8; hp < 16; ++hp) attT[hp][tid] = 0;
    }
    #pragma unroll
    for (int it = 0; it < 4; ++it) {   // edge -> bf16 LDS
        int fid = (tid + 512*it)*4;
        int j = fid >> 6, e = fid & 63;
        uint lo = (uint)f2b(ef[it].x) | ((uint)f2b(ef[it].y) << 16);
        uint hi = (uint)f2b(ef[it].z) | ((uint)f2b(ef[it].w) << 16);
        *(uint2*)&edsA[j][e] = make_uint2(lo, hi);
    }
    __syncthreads();

    {   // logits MFMA: D[j-local][h]; wave w = j-tile mt
        int mt = w;
        floatx4 acc = {0,0,0,0};
        #pragma unroll
        for (int kt = 0; kt < 2; ++kt) {
            short8 af = *(short8*)&edsA[mt*16 + r][kt*32 + g*8];
            short8 bf = *(short8*)&qkpL[r][kt*32 + g*8];
            acc = __builtin_amdgcn_mfma_f32_16x16x32_bf16(af, bf, acc, 0,0,0);
        }
        if (r < 8) {
            #pragma unroll
            for (int i = 0; i < 4; ++i) {
                int j = mt*16 + 4*g + i;
                attL[r][j] = (mval[j] > 0.5f) ? acc[i] : SENT;
            }
        }
    }
    __syncthreads();

    {   // softmax: wave w = head w
        int h = w;
        float v0 = attL[h][lane];
        float v1 = attL[h][64 + lane];
        float mx = fmaxf(v0, v1);
        #pragma unroll
        for (int off = 32; off >= 1; off >>= 1) mx = fmaxf(mx, __shfl_xor(mx, off));
        float e0 = __expf(v0 - mx), e1 = __expf(v1 - mx);
        float smv = e0 + e1;
        #pragma unroll
        for (int off = 32; off >= 1; off >>= 1) smv += __shfl_xor(smv, off);
        float inv = 1.0f / smv;
        attT[h][lane]      = f2b(e0 * inv);
        attT[h][64 + lane] = f2b(e1 * inv);
    }
    __syncthreads();

    if (w < 4) {   // agg MFMA: D[h][e]; wave w = e-tile
        floatx4 acc = {0,0,0,0};
        #pragma unroll
        for (int kt = 0; kt < 4; ++kt) {
            short8 a2 = *(short8*)&attT[r][kt*32 + g*8];
            short8 b2;
            #pragma unroll
            for (int jj = 0; jj < 8; ++jj)
                b2[jj] = (short)edsA[kt*32 + g*8 + jj][w*16 + r];
            acc = __builtin_amdgcn_mfma_f32_16x16x32_bf16(a2, b2, acc, 0,0,0);
        }
        #pragma unroll
        for (int i = 0; i < 4; ++i) {
            int h = 4*g + i;
            if (h < 8)
                aggO[(size_t)row*512 + h*64 + w*16 + r] = f2b(acc[i]);
        }
    }
}

// ---------------- K3: y + out projection (r9 exact) ------------------------
// grid 128 = (rt 32 x ob 4), 256 thr. Raw Wv-edge / Wp rows as B-frags.
__global__ __launch_bounds__(256, 2)
void k3_out(const float* __restrict__ vnode, const ushort* __restrict__ aggI,
            const float* __restrict__ Wv, const float* __restrict__ Wp,
            const float* __restrict__ bp, float* __restrict__ out) {
    __shared__ ushort yL[16][264];
    int tid = threadIdx.x;
    int w = tid >> 6, lane = tid & 63, g = lane >> 4, r = lane & 15;
    int rt = blockIdx.x >> 2, ob = blockIdx.x & 3;
    int r0 = rt*16, o0 = ob*64;

    {   // y phase: wave w -> 4 (head, c-subtile) pairs
        #pragma unroll
        for (int pi = 0; pi < 4; ++pi) {
            int p = w*4 + pi, h = p >> 1, ntl = p & 1;
            int c = h*32 + ntl*16 + r;
            floatx4 acc;
            #pragma unroll
            for (int i = 0; i < 4; ++i)
                acc[i] = vnode[(size_t)(r0 + 4*g + i)*256 + c];
            #pragma unroll
            for (int kt = 0; kt < 2; ++kt) {
                short8 af = *(const short8*)&aggI[(size_t)(r0 + r)*512 + h*64 + kt*32 + g*8];
                const float* wr = Wv + (size_t)c*320 + 256 + kt*32 + g*8;
                short8 bf = pk8(*(const float4*)wr, *(const float4*)(wr + 4));
                acc = __builtin_amdgcn_mfma_f32_16x16x32_bf16(af, bf, acc, 0,0,0);
            }
            #pragma unroll
            for (int i = 0; i < 4; ++i)
                yL[4*g + i][c] = f2b(acc[i]);
        }
    }
    __syncthreads();

    {   // out phase: wave w = o-subtile
        int o = o0 + w*16 + r;
        floatx4 acc = {0,0,0,0};
        const float* wr = Wp + (size_t)o*256;
        #pragma unroll
        for (int kt = 0; kt < 8; ++kt) {
            int k0 = kt*32 + g*8;
            short8 af = *(short8*)&yL[r][k0];
            short8 bf = pk8(*(const float4*)&wr[k0], *(const float4*)&wr[k0+4]);
            acc = __builtin_amdgcn_mfma_f32_16x16x32_bf16(af, bf, acc, 0,0,0);
        }
        float bb = bp[o];
        #pragma unroll
        for (int i = 0; i < 4; ++i)
            out[(size_t)(r0 + 4*g + i)*256 + o] = acc[i] + bb;
    }
}

extern "C" void kernel_launch(void* const* d_in, const int* in_sizes, int n_in,
                              void* d_out, int out_size, void* d_ws, size_t ws_size,
                              hipStream_t stream) {
    (void)in_sizes; (void)n_in; (void)out_size; (void)ws_size;
    const float* x    = (const float*)d_in[0];
    // d_in[1] aux_x: unused by reference
    const int*   msk  = (const int*)d_in[2];
    const float* edge = (const float*)d_in[3];
    const float* Wq   = (const float*)d_in[4];
    const float* bq   = (const float*)d_in[5];
    const float* Wk   = (const float*)d_in[6];
    // d_in[7] bk: constant over j -> cancels in softmax
    const float* Wv   = (const float*)d_in[8];
    const float* bv   = (const float*)d_in[9];
    const float* Wp   = (const float*)d_in[10];
    const float* bp   = (const float*)d_in[11];
    float* out = (float*)d_out;
    float* ws  = (float*)d_ws;

    ushort* qkp   = (ushort*)(ws + OFF_QKP);
    ushort* agg   = (ushort*)(ws + OFF_AGG);
    float*  vnode = ws + OFF_VNODE;

    k1_proj<<<256, 256, 0, stream>>>(x, Wq, Wv, Wk, bq, bv, vnode, qkp);
    k2_attn<<<512, 512, 0, stream>>>(edge, msk, qkp, agg);
    k3_out<<<128, 256, 0, stream>>>(vnode, agg, Wv, Wp, bp, out);
}